// Round 13
// baseline (54.573 us; speedup 1.0000x reference)
//
#include <hip/hip_runtime.h>

#define NN 160      // nodes
#define BB 128      // batch
#define HH 256      // hidden
#define EE 5120     // edges
#define ST 128      // state dim
#define AC 32       // action dim
#define IH 80       // i-half rows

typedef __attribute__((ext_vector_type(8))) short short8;
typedef __attribute__((ext_vector_type(4))) short bf16x4;
typedef __attribute__((ext_vector_type(4))) float f32x4;
typedef unsigned short us;

__device__ inline us f2b(float f) {
    unsigned u = __builtin_bit_cast(unsigned, f);
    unsigned r = (u + 0x7FFFu + ((u >> 16) & 1u)) >> 16;
    return (us)r;
}
__device__ inline float b2f(us h) {
    return __builtin_bit_cast(float, (unsigned)h << 16);
}

// ---------- K1: graph rows + Pb/Mb (int-exact) + weight transposes + out init ----------
__global__ __launch_bounds__(256)
void k_pre(const int* __restrict__ ei, const float* __restrict__ W1,
           const float* __restrict__ W2, const float* __restrict__ state,
           const float* __restrict__ bo, us* __restrict__ Pb,
           us* __restrict__ Mb, us* __restrict__ W1t, us* __restrict__ W2t,
           float* __restrict__ out)
{
    const int bx = blockIdx.x, tid = threadIdx.x;
    if (bx < NN) {
        __shared__ int crow[NN];
        __shared__ unsigned abit[NN * NN / 32];   // 3.2 KB
        __shared__ float invdeg;
        if (tid < NN) crow[tid] = 0;
        for (int i = tid; i < NN * NN / 32; i += 256) abit[i] = 0;
        __syncthreads();
        for (int e = tid; e < EE; e += 256) {
            int s = ei[e], d = ei[EE + e];
            int p = d * NN + s;
            atomicOr(&abit[p >> 5], 1u << (p & 31));
            if (d == bx) atomicAdd(&crow[s], 1);
        }
        if (tid < NN) {
            int p = tid * NN + tid;
            atomicOr(&abit[p >> 5], 1u << (p & 31));
        }
        __syncthreads();
        if (tid == 0) {
            int dg = 0;
            for (int j = 0; j < NN; j++) dg += crow[j];
            invdeg = 1.0f / (float)(dg < 1 ? 1 : dg);
        }
        __syncthreads();
        if (tid < NN) {
            int s = 0;
            for (int k = 0; k < NN; k++) {
                int p = k * NN + tid;
                if (abit[p >> 5] & (1u << (p & 31))) s += crow[k];
            }
            Pb[bx * NN + tid] = f2b((float)s * invdeg);
            Mb[bx * NN + tid] = f2b((float)crow[tid] * invdeg);
        }
    } else if (bx < NN + 160) {                   // W1t: 256x160
        int idx = (bx - NN) * 256 + tid;
        int n = idx / NN, k = idx - n * NN;
        W1t[idx] = f2b(W1[k * HH + n]);
    } else if (bx < NN + 160 + 256) {             // W2t: 256x256
        int idx = (bx - NN - 160) * 256 + tid;
        int n = idx >> 8, k = idx & 255;
        W2t[idx] = f2b(W2[k * HH + n]);
    } else {                                      // out init: 128x128
        int idx = (bx - NN - 160 - 256) * 256 + tid;
        out[idx] = state[idx] + bo[idx & 127];
    }
}

// LDS region offsets (in shorts)
#define YOFF   0        // [2][160][40] dbuf Y          (25600 B)
#define W1OFF  12800    // [128][168]   W1t-half / h1   (43008 B)
#define MBOFF  34304    // [80][168]    Mb i-half       (26880 B)
#define TSOFF  47744    // [80][136]    t half          (21760 B)
#define W2OFF  58624    // [2][256][40] W2t dbuf        (40960 B)
// total 79104 shorts = 158208 B (+ xb 640 B)

// ---------- K2: 256 blocks = (i-half, batch), 256 threads = 4 FAT waves ----------
// G1 (dup): D[i 160][h 128] K=160 -> h1[h][i]   waves 2(i)x2(h): 9 reads/20 MFMA
// G2:       D[h 128][i' 80] K=160 -> ts[i'][h]  waves 4(h)x1   : 7 reads/10 MFMA, 0 barriers
// G3:       D[i' 80][h' 256] K=128/hh (acc in regs across hh)   waves 1x4: 9/20
__global__ __launch_bounds__(256, 1)
void k_mega(const us* __restrict__ Pb, const float* __restrict__ state,
            const float* __restrict__ action, const us* __restrict__ W1t,
            const float* __restrict__ b1, const us* __restrict__ Mb,
            const us* __restrict__ W2t, const float* __restrict__ b2,
            const float* __restrict__ Wo, float* __restrict__ out)
{
    __shared__ __align__(16) us SH[79104];
    __shared__ float xb[NN];
    const int ihalf = blockIdx.x, b = blockIdx.y, i_base = ihalf * IH;
    const int tid = threadIdx.x, lane = tid & 63, w = tid >> 6;  // 4 waves
    const int rl = lane & 15, kq = lane >> 4;
    const int wr = w >> 1, wc = w & 1;

    if (tid < NN) xb[tid] = (tid < ST) ? state[b * ST + tid]
                                       : action[b * AC + (tid - ST)];
    // stage Mb i-half: 80x160 -> [80][168]
    for (int c = tid; c < 1600; c += 256) {
        int r = c / 20, col = (c % 20) * 8;
        *(short8*)&SH[MBOFF + r * 168 + col] =
            *(const short8*)&Mb[(size_t)(i_base + r) * NN + col];
    }
    __syncthreads();

    f32x4 acc3[5][4];
#pragma unroll
    for (int f = 0; f < 5; f++)
#pragma unroll
        for (int j = 0; j < 4; j++) acc3[f][j] = f32x4{0.f, 0.f, 0.f, 0.f};

    for (int hh = 0; hh < 2; hh++) {
        const int ho = hh * 128;
        // ---- stage W1t-half: 128x160 -> [128][168] (overwrites prev h1)
        for (int c = tid; c < 2560; c += 256) {
            int r = c / 20, col = (c % 20) * 8;
            *(short8*)&SH[W1OFF + r * 168 + col] =
                *(const short8*)&W1t[(size_t)(ho + r) * NN + col];
        }
        // ---- stage Y step0 into buf0 (chunks tid, tid+256, tid<128: tid+512)
        {
            int c0 = tid, c1 = tid + 256;
            short8 p0 = *(const short8*)&Pb[(c0 >> 2) * NN + (c0 & 3) * 8];
            short8 p1 = *(const short8*)&Pb[(c1 >> 2) * NN + (c1 & 3) * 8];
            short8 y0, y1;
#pragma unroll
            for (int u = 0; u < 8; u++) {
                y0[u] = (short)f2b(b2f((us)p0[u]) * xb[(c0 & 3) * 8 + u]);
                y1[u] = (short)f2b(b2f((us)p1[u]) * xb[(c1 & 3) * 8 + u]);
            }
            *(short8*)&SH[YOFF + (c0 >> 2) * 40 + (c0 & 3) * 8] = y0;
            *(short8*)&SH[YOFF + (c1 >> 2) * 40 + (c1 & 3) * 8] = y1;
            if (tid < 128) {
                int c2 = tid + 512;
                short8 p2 = *(const short8*)&Pb[(c2 >> 2) * NN + (c2 & 3) * 8];
                short8 y2;
#pragma unroll
                for (int u = 0; u < 8; u++)
                    y2[u] = (short)f2b(b2f((us)p2[u]) * xb[(c2 & 3) * 8 + u]);
                *(short8*)&SH[YOFF + (c2 >> 2) * 40 + (c2 & 3) * 8] = y2;
            }
        }
        __syncthreads();

        // ---- G1: 5 K-steps, Y dbuf (1 barrier/step)
        f32x4 acc1[5][4];
#pragma unroll
        for (int f = 0; f < 5; f++)
#pragma unroll
            for (int j = 0; j < 4; j++) acc1[f][j] = f32x4{0.f, 0.f, 0.f, 0.f};

        for (int kk = 0; kk < 5; kk++) {
            const int k0 = kk * 32;
            const int cur = (kk & 1) * 6400, nb = ((kk + 1) & 1) * 6400;
            short8 p0, p1, p2;
            if (kk < 4) {   // T14 issue-early
                int c0 = tid, c1 = tid + 256;
                p0 = *(const short8*)&Pb[(c0 >> 2) * NN + k0 + 32 + (c0 & 3) * 8];
                p1 = *(const short8*)&Pb[(c1 >> 2) * NN + k0 + 32 + (c1 & 3) * 8];
                if (tid < 128) {
                    int c2 = tid + 512;
                    p2 = *(const short8*)&Pb[(c2 >> 2) * NN + k0 + 32 + (c2 & 3) * 8];
                }
            }
            short8 af[5], bf[4];
#pragma unroll
            for (int f = 0; f < 5; f++)
                af[f] = *(const short8*)&SH[YOFF + cur + (wr * 80 + f * 16 + rl) * 40 + kq * 8];
#pragma unroll
            for (int j = 0; j < 4; j++)
                bf[j] = *(const short8*)&SH[W1OFF + (wc * 64 + j * 16 + rl) * 168 + k0 + kq * 8];
#pragma unroll
            for (int f = 0; f < 5; f++)
#pragma unroll
                for (int j = 0; j < 4; j++)
                    acc1[f][j] = __builtin_amdgcn_mfma_f32_16x16x32_bf16(
                        af[f], bf[j], acc1[f][j], 0, 0, 0);
            if (kk < 4) {   // write-late to other buffer
                int c0 = tid, c1 = tid + 256;
                short8 y0, y1;
#pragma unroll
                for (int u = 0; u < 8; u++) {
                    y0[u] = (short)f2b(b2f((us)p0[u]) * xb[k0 + 32 + (c0 & 3) * 8 + u]);
                    y1[u] = (short)f2b(b2f((us)p1[u]) * xb[k0 + 32 + (c1 & 3) * 8 + u]);
                }
                *(short8*)&SH[YOFF + nb + (c0 >> 2) * 40 + (c0 & 3) * 8] = y0;
                *(short8*)&SH[YOFF + nb + (c1 >> 2) * 40 + (c1 & 3) * 8] = y1;
                if (tid < 128) {
                    int c2 = tid + 512;
                    short8 y2;
#pragma unroll
                    for (int u = 0; u < 8; u++)
                        y2[u] = (short)f2b(b2f((us)p2[u]) * xb[k0 + 32 + (c2 & 3) * 8 + u]);
                    *(short8*)&SH[YOFF + nb + (c2 >> 2) * 40 + (c2 & 3) * 8] = y2;
                }
            }
            __syncthreads();
        }
        // ---- G1 epi: h1[h][i-packed] over dead W1t region
#pragma unroll
        for (int j = 0; j < 4; j++) {
            int h = wc * 64 + j * 16 + rl;
            float bias = b1[ho + h];
#pragma unroll
            for (int f = 0; f < 5; f++) {
                int i0 = wr * 80 + f * 16 + kq * 4;
                bf16x4 v;
#pragma unroll
                for (int r = 0; r < 4; r++) {
                    float t = acc1[f][j][r] + bias;
                    v[r] = (short)f2b(t > 0.f ? t : 0.f);
                }
                *(bf16x4*)&SH[W1OFF + h * 168 + i0] = v;
            }
        }
        __syncthreads();

        // ---- G2: barrier-free (h1 + Mb resident). wave w: h rows [32w,32w+32)
        f32x4 acc2[2][5];
#pragma unroll
        for (int f = 0; f < 2; f++)
#pragma unroll
            for (int j = 0; j < 5; j++) acc2[f][j] = f32x4{0.f, 0.f, 0.f, 0.f};
        for (int kk = 0; kk < 5; kk++) {
            const int k0 = kk * 32;
            short8 a2[2], b2v[5];
#pragma unroll
            for (int f = 0; f < 2; f++)
                a2[f] = *(const short8*)&SH[W1OFF + (w * 32 + f * 16 + rl) * 168 + k0 + kq * 8];
#pragma unroll
            for (int j = 0; j < 5; j++)
                b2v[j] = *(const short8*)&SH[MBOFF + (j * 16 + rl) * 168 + k0 + kq * 8];
#pragma unroll
            for (int f = 0; f < 2; f++)
#pragma unroll
                for (int j = 0; j < 5; j++)
                    acc2[f][j] = __builtin_amdgcn_mfma_f32_16x16x32_bf16(
                        a2[f], b2v[j], acc2[f][j], 0, 0, 0);
        }
        // ---- G2 epi: ts[i'][h-packed] (region disjoint from h1/Mb)
#pragma unroll
        for (int f = 0; f < 2; f++) {
            int h0 = w * 32 + f * 16 + kq * 4;
#pragma unroll
            for (int j = 0; j < 5; j++) {
                int ip = j * 16 + rl;
                bf16x4 v;
#pragma unroll
                for (int r = 0; r < 4; r++)
                    v[r] = (short)f2b(acc2[f][j][r]);
                *(bf16x4*)&SH[TSOFF + ip * 136 + h0] = v;
            }
        }
        // stage W2t step0 (row tid, 4 chunks) into buf0
#pragma unroll
        for (int c = 0; c < 4; c++)
            *(short8*)&SH[W2OFF + tid * 40 + c * 8] =
                *(const short8*)&W2t[(size_t)tid * HH + ho + c * 8];
        __syncthreads();

        // ---- G3 partial: 4 K-steps over this half, W2t dbuf (1 barrier/step)
        for (int kk = 0; kk < 4; kk++) {
            const int cur = (kk & 1) * 10240;
            short8 wn0, wn1, wn2, wn3;
            if (kk < 3) {   // issue-early
                wn0 = *(const short8*)&W2t[(size_t)tid * HH + ho + (kk + 1) * 32 + 0];
                wn1 = *(const short8*)&W2t[(size_t)tid * HH + ho + (kk + 1) * 32 + 8];
                wn2 = *(const short8*)&W2t[(size_t)tid * HH + ho + (kk + 1) * 32 + 16];
                wn3 = *(const short8*)&W2t[(size_t)tid * HH + ho + (kk + 1) * 32 + 24];
            }
            short8 a3[5], b3[4];
#pragma unroll
            for (int f = 0; f < 5; f++)
                a3[f] = *(const short8*)&SH[TSOFF + (f * 16 + rl) * 136 + kk * 32 + kq * 8];
#pragma unroll
            for (int j = 0; j < 4; j++)
                b3[j] = *(const short8*)&SH[W2OFF + cur + (w * 64 + j * 16 + rl) * 40 + kq * 8];
#pragma unroll
            for (int f = 0; f < 5; f++)
#pragma unroll
                for (int j = 0; j < 4; j++)
                    acc3[f][j] = __builtin_amdgcn_mfma_f32_16x16x32_bf16(
                        a3[f], b3[j], acc3[f][j], 0, 0, 0);
            if (kk < 3) {   // write-late into idle buffer
                int o = W2OFF + (cur ^ 10240) + tid * 40;
                *(short8*)&SH[o + 0]  = wn0;
                *(short8*)&SH[o + 8]  = wn1;
                *(short8*)&SH[o + 16] = wn2;
                *(short8*)&SH[o + 24] = wn3;
            }
            __syncthreads();
        }
    } // hh

    // ---- epi: bias+relu, in-lane pool over 20 i'-rows, slot by kq ----
    float* pp  = (float*)SH;          // [4][256] over dead Y region
    float* pts = pp + 1024;           // [2][128]
    float* pph = pp + 1280;           // [256]
#pragma unroll
    for (int j = 0; j < 4; j++) {
        int h = w * 64 + j * 16 + rl;
        float bias = b2[h];
        float s = 0.f;
#pragma unroll
        for (int f = 0; f < 5; f++)
#pragma unroll
            for (int r = 0; r < 4; r++) {
                float v = acc3[f][j][r] + bias;
                s += v > 0.f ? v : 0.f;
            }
        pp[kq * 256 + h] = s;
    }
    __syncthreads();
    pph[tid] = pp[tid] + pp[256 + tid] + pp[512 + tid] + pp[768 + tid];
    __syncthreads();
    // ---- head: out[b][s] += (sum_h ph[h]*Wo[h][s]) / NN ----
    {
        const int q = tid >> 7, s2 = tid & 127;
        float part = 0.f;
        for (int hx = q * 128; hx < q * 128 + 128; hx++)
            part += pph[hx] * Wo[hx * ST + s2];     // pph: wave-broadcast read
        pts[q * 128 + s2] = part;
        __syncthreads();
        if (tid < ST)
            atomicAdd(&out[b * ST + tid], (pts[tid] + pts[128 + tid]) * (1.0f / NN));
    }
}

extern "C" void kernel_launch(void* const* d_in, const int* in_sizes, int n_in,
                              void* d_out, int out_size, void* d_ws, size_t ws_size,
                              hipStream_t stream) {
    const float* state  = (const float*)d_in[0];
    const float* action = (const float*)d_in[1];
    const int*   ei     = (const int*)d_in[2];
    const float* W1     = (const float*)d_in[3];
    const float* b1     = (const float*)d_in[4];
    const float* W2     = (const float*)d_in[5];
    const float* b2     = (const float*)d_in[6];
    const float* Wo     = (const float*)d_in[7];
    const float* bo     = (const float*)d_in[8];
    float* out = (float*)d_out;

    char* ws = (char*)d_ws;
    size_t off = 0;
    auto alloc = [&](size_t bytes) {
        void* p = ws + off;
        off += (bytes + 255) & ~(size_t)255;
        return p;
    };
    us* Pb  = (us*)alloc(NN * NN * 2);
    us* Mb  = (us*)alloc(NN * NN * 2);
    us* W1t = (us*)alloc((size_t)HH * NN * 2);
    us* W2t = (us*)alloc((size_t)HH * HH * 2);

    k_pre<<<NN + 160 + 256 + 64, 256, 0, stream>>>(ei, W1, W2, state, bo,
                                                   Pb, Mb, W1t, W2t, out);
    {
        dim3 g(2, BB);   // (i-half, batch) = 256 blocks
        k_mega<<<g, 256, 0, stream>>>(Pb, state, action, W1t, b1, Mb, W2t, b2,
                                      Wo, out);
    }
}